// Round 4
// baseline (204.708 us; speedup 1.0000x reference)
//
#include <hip/hip_runtime.h>
#include <stdint.h>

// MultiHeadCrossAttention: B=2, SQ=SK=2048, D=1024, H=16, Dh=64, scale=1/8.
// fp32 in/out, bf16 MFMA internal.
// R14: attn rewritten on 32x32 MFMAs with swapped QK^T and fully in-register P.
//      S^T = mfma_32x32x16(K,Q) leaves each lane holding 16 S-values of its OWN
//      q row at kv=(r&3)+8(r>>2)+4hi — exactly the A-frag layout of
//      mfma_f32_32x32x8_bf16 (k=(l>>5)*4+j). So softmax->PV needs NO cross-lane
//      exchange and NO P LDS round trip (R13 spent ~64 v_mov + 24 ds ops + fence
//      per kt on it; VALUBusy 35%). l = in-lane sum + one shfl_xor(32). Ps LDS
//      deleted (49152->32768 B). Staging/prefetch/barriers unchanged.
// R13/R12: gemm_qkv 256^2 4-quadrant-phase counted-vmcnt schedule (passed, off
//      top-5). gemm_out/prep unchanged.

typedef unsigned short u16b;
typedef __attribute__((ext_vector_type(4))) short short4v;
typedef __attribute__((ext_vector_type(8))) short short8v;
typedef __attribute__((ext_vector_type(4))) float float4v;
typedef __attribute__((ext_vector_type(16))) float float16v;
typedef __attribute__((ext_vector_type(2))) unsigned int uint2v;

#if __has_builtin(__builtin_amdgcn_exp2f)
__device__ __forceinline__ float exp2_fast(float x){ return __builtin_amdgcn_exp2f(x); }
#else
__device__ __forceinline__ float exp2_fast(float x){ return exp2f(x); }
#endif

__device__ __forceinline__ u16b f2bf(float f) {
  union { float f; unsigned int i; } v; v.f = f;
  return (u16b)((v.i + 0x7fffu + ((v.i >> 16) & 1u)) >> 16);  // RNE
}
__device__ __forceinline__ void gl_lds16(const u16b* g, u16b* l) {
  __builtin_amdgcn_global_load_lds(
      (const __attribute__((address_space(1))) void*)g,
      (__attribute__((address_space(3))) void*)l, 16, 0, 0);
}

#define FENCE_BARRIER() do { asm volatile("" ::: "memory"); \
  __builtin_amdgcn_s_barrier(); asm volatile("" ::: "memory"); } while(0)
#define LGKM0() do { asm volatile("s_waitcnt lgkmcnt(0)" ::: "memory"); \
  __builtin_amdgcn_sched_barrier(0); } while(0)
#define VMCNT(n) do { asm volatile("s_waitcnt vmcnt(" #n ")" ::: "memory"); \
  __builtin_amdgcn_sched_barrier(0); } while(0)

// ---------------- prep: y=0,1 -> cvt x1/x2 fp32->bf16 ; y=2..5 -> transpose W[y-2] ---
__global__ __launch_bounds__(256) void prep(
    const float* __restrict__ x1, const float* __restrict__ x2,
    const float* __restrict__ W0, const float* __restrict__ W1,
    const float* __restrict__ W2, const float* __restrict__ W3,
    u16b* __restrict__ x1b, u16b* __restrict__ x2b, u16b* __restrict__ WT) {
  const int tid = threadIdx.x;
  const int mode = blockIdx.y;
  if (mode < 2) {
    const float* src = mode ? x2 : x1;
    u16b* dst = mode ? x2b : x1b;
    const int n4 = 1024*1024;             // 4Mi elems / 4
    int i = blockIdx.x * 256 + tid;
    const int stride = gridDim.x * 256;
    for (; i < n4; i += stride) {
      float4v v = ((const float4v*)src)[i];
      short4v o;
      o[0]=(short)f2bf(v[0]); o[1]=(short)f2bf(v[1]);
      o[2]=(short)f2bf(v[2]); o[3]=(short)f2bf(v[3]);
      ((short4v*)dst)[i] = o;
    }
  } else {
    __shared__ u16b tile[32][33];
    const int z = mode - 2;
    const float* src = (z==0) ? W0 : (z==1) ? W1 : (z==2) ? W2 : W3;
    u16b* dst = WT + (size_t)z * (1024*1024);
    const int x = tid & 31, y = tid >> 5;   // 32 x 8
    const int bx = (blockIdx.x & 31) * 32, by = (blockIdx.x >> 5) * 32;
#pragma unroll
    for (int j=0;j<4;++j)
      tile[y*4+j][x] = f2bf(src[(size_t)(by + y*4+j)*1024 + bx + x]);
    __syncthreads();
#pragma unroll
    for (int j=0;j<4;++j)
      dst[(size_t)(bx + y*4+j)*1024 + by + x] = tile[x][y*4+j];
  }
}

// ---------------- 256x256 8-phase GEMM core (unchanged from R13) --------------------
template<bool BIAS_ROW>
__device__ __forceinline__ void gemm256_core(
    u16b* __restrict__ As, u16b* __restrict__ Bs,
    const u16b* __restrict__ A, const u16b* __restrict__ Bt,
    const float* __restrict__ bias, u16b* __restrict__ C,
    int N, int K, int bm, int bn, float oscale) {
  constexpr int ASTR = 256*64, BSTR = 256*64;
  const int tid = threadIdx.x;
  const int lane = tid & 63, wave = tid >> 6;
  const int wr = wave >> 2, wc = wave & 3;      // 2x4 waves in a quadrant
  const int l15 = lane & 15, l4 = lane >> 4;

  auto stage_half = [&](const u16b* __restrict__ G, int row0, int k0,
                        u16b* __restrict__ Lbase) {
#pragma unroll
    for (int j=0;j<2;++j) {                     // 128 rows x 8 chunks, 2 loads/thr
      int idx = j*512 + tid;
      int row = idx >> 3, seg = idx & 7;
      int segg = seg ^ (row & 7);
      gl_lds16(&G[(size_t)(row0+row)*K + k0 + segg*8], &Lbase[idx*8]);
    }
  };

  float4v acc[2][2][4][2];
#pragma unroll
  for (int qm=0;qm<2;++qm)
#pragma unroll
  for (int qn=0;qn<2;++qn)
#pragma unroll
  for (int m=0;m<4;++m)
#pragma unroll
  for (int n=0;n<2;++n) acc[qm][qn][m][n] = (float4v){0.f,0.f,0.f,0.f};

  const int NK = K >> 6;
  // ---- prologue: tile0 all 4 halves + tile1 A0,B0 (12 loads/thr) --------------
  stage_half(A,  bm+0,   0,  As + 0);           // t0:A0
  stage_half(Bt, bn+0,   0,  Bs + 0);           // t0:B0
  stage_half(A,  bm+128, 0,  As + 128*64);      // t0:A1
  stage_half(Bt, bn+128, 0,  Bs + 128*64);      // t0:B1
  stage_half(A,  bm+0,   64, As + ASTR);        // t1:A0
  stage_half(Bt, bn+0,   64, Bs + BSTR);        // t1:B0
  VMCNT(4);                                     // t0 fully landed; t1:A0,B0 in flight
  FENCE_BARRIER();

  int cur = 0;
  for (int t = 0; t < NK; ++t) {
    u16b* Ac = As + cur*ASTR;  u16b* Bc = Bs + cur*BSTR;
    u16b* An = As + (cur^1)*ASTR;  u16b* Bn = Bs + (cur^1)*BSTR;
    const int k1 = (t+1) << 6, k2 = (t+2) << 6;
    short8v af[4][2], bf0[2][2], bf1[2][2];

    // ---- ph1: quad (0,0). reads A0 + B0; stage (t+1):A1 -> next buf ----------
#pragma unroll
    for (int m=0;m<4;++m)
#pragma unroll
      for (int ks=0;ks<2;++ks)
        af[m][ks] = *(const short8v*)&Ac[(0*128 + wr*64 + m*16 + l15)*64
                                         + (((ks*4+l4) ^ (l15&7))*8)];
#pragma unroll
    for (int n=0;n<2;++n)
#pragma unroll
      for (int ks=0;ks<2;++ks)
        bf0[n][ks] = *(const short8v*)&Bc[(0*128 + wc*32 + n*16 + l15)*64
                                          + (((ks*4+l4) ^ (l15&7))*8)];
    if (t+1 < NK) stage_half(A, bm+128, k1, An + 128*64);
    FENCE_BARRIER();
    LGKM0();
    __builtin_amdgcn_s_setprio(1);
#pragma unroll
    for (int m=0;m<4;++m)
#pragma unroll
      for (int n=0;n<2;++n)
#pragma unroll
        for (int ks=0;ks<2;++ks)
          acc[0][0][m][n] = __builtin_amdgcn_mfma_f32_16x16x32_bf16(
              af[m][ks], bf0[n][ks], acc[0][0][m][n], 0, 0, 0);
    __builtin_amdgcn_s_setprio(0);
    FENCE_BARRIER();

    // ---- ph2: quad (0,1). reads B1 (af reused); stage (t+1):B1 -> next buf ---
#pragma unroll
    for (int n=0;n<2;++n)
#pragma unroll
      for (int ks=0;ks<2;++ks)
        bf1[n][ks] = *(const short8v*)&Bc[(1*128 + wc*32 + n*16 + l15)*64
                                          + (((ks*4+l4) ^ (l15&7))*8)];
    if (t+1 < NK) stage_half(Bt, bn+128, k1, Bn + 128*64);
    FENCE_BARRIER();
    LGKM0();
    __builtin_amdgcn_s_setprio(1);
#pragma unroll
    for (int m=0;m<4;++m)
#pragma unroll
      for (int n=0;n<2;++n)
#pragma unroll
        for (int ks=0;ks<2;++ks)
          acc[0][1][m][n] = __builtin_amdgcn_mfma_f32_16x16x32_bf16(
              af[m][ks], bf1[n][ks], acc[0][1][m][n], 0, 0, 0);
    __builtin_amdgcn_s_setprio(0);
    FENCE_BARRIER();

    // ---- ph3: quad (1,0). reads A1 (bf0 from regs); stage (t+2):A0 -> cur.A0 -
#pragma unroll
    for (int m=0;m<4;++m)
#pragma unroll
      for (int ks=0;ks<2;++ks)
        af[m][ks] = *(const short8v*)&Ac[(1*128 + wr*64 + m*16 + l15)*64
                                         + (((ks*4+l4) ^ (l15&7))*8)];
    if (t+2 < NK) stage_half(A, bm+0, k2, Ac + 0);
    FENCE_BARRIER();
    LGKM0();
    __builtin_amdgcn_s_setprio(1);
#pragma unroll
    for (int m=0;m<4;++m)
#pragma unroll
      for (int n=0;n<2;++n)
#pragma unroll
        for (int ks=0;ks<2;++ks)
          acc[1][0][m][n] = __builtin_amdgcn_mfma_f32_16x16x32_bf16(
              af[m][ks], bf0[n][ks], acc[1][0][m][n], 0, 0, 0);
    __builtin_amdgcn_s_setprio(0);
    FENCE_BARRIER();

    // ---- ph4: quad (1,1). all operands in regs; stage (t+2):B0 -> cur.B0 -----
    if (t+2 < NK) stage_half(Bt, bn+0, k2, Bc + 0);
    FENCE_BARRIER();
    LGKM0();
    __builtin_amdgcn_s_setprio(1);
#pragma unroll
    for (int m=0;m<4;++m)
#pragma unroll
      for (int n=0;n<2;++n)
#pragma unroll
        for (int ks=0;ks<2;++ks)
          acc[1][1][m][n] = __builtin_amdgcn_mfma_f32_16x16x32_bf16(
              af[m][ks], bf1[n][ks], acc[1][1][m][n], 0, 0, 0);
    __builtin_amdgcn_s_setprio(0);
    if (t == NK-2) { VMCNT(0); }                 // tail: next tile has nothing newer
    else          { VMCNT(4); }                  // tile t+1 fully landed; 2 halves fly
    FENCE_BARRIER();
    cur ^= 1;
  }

  // ---- epilogue ---------------------------------------------------------------
#pragma unroll
  for (int qm=0;qm<2;++qm)
#pragma unroll
  for (int qn=0;qn<2;++qn)
#pragma unroll
  for (int n=0;n<2;++n) {
    int col = bn + qn*128 + wc*32 + n*16 + l15;
    float bbc = BIAS_ROW ? 0.f : bias[col];
#pragma unroll
    for (int m=0;m<4;++m) {
      int row0 = bm + qm*128 + wr*64 + m*16 + l4*4;
#pragma unroll
      for (int r=0;r<4;++r) {
        float bb = BIAS_ROW ? bias[row0+r] : bbc;
        float v = (acc[qm][qn][m][n][r] + bb) * oscale;
        C[(size_t)(row0+r)*N + col] = f2bf(v);
      }
    }
  }
}

// Q / K / V^T projections, 192 blocks x 512 threads, per-z XCD-chunked swizzle.
__global__ __launch_bounds__(512, 2) void gemm_qkv256(
    const u16b* __restrict__ x1b, const u16b* __restrict__ x2b,
    const u16b* __restrict__ WT, const float* __restrict__ bq,
    const float* __restrict__ bk, const float* __restrict__ bv,
    u16b* __restrict__ QKV) {
  __shared__ __align__(16) u16b As[2*256*64];
  __shared__ __align__(16) u16b Bs[2*256*64];
  const int f = blockIdx.x;
  const int z = f >> 6;                      // 0=Q, 1=K, 2=V^T
  const int u = f & 63;
  const int w = ((u & 7) << 3) | (u >> 3);   // xcd = u&7 gets 8 contiguous tiles
  const size_t Mi = 1024*1024;
  const float QSCALE = 0.125f * 1.4426950408889634f;   // 1/sqrt(Dh) * log2(e)
  if (z == 2) {
    int bm = (w >> 4) * 256;                 // WvT rows (d)
    int bn = (w & 15) * 256;                 // tokens
    gemm256_core<true>(As, Bs, WT + 2*Mi, x2b, bv, QKV + 8*Mi,
                       4096, 1024, bm, bn, 1.0f);
  } else {
    int bm = (w >> 2) * 256;                 // tokens
    int bn = (w & 3) * 256;                  // d_model cols
    gemm256_core<false>(As, Bs, z ? x2b : x1b, WT + (size_t)z*Mi,
                        z ? bk : bq, QKV + (size_t)z*4*Mi,
                        1024, 1024, bm, bn, z ? 1.0f : QSCALE);
  }
}

// ---------------- 128-tile GEMM core (gemm_out): 2-phase dbuf pipeline --------------
template<int BN, bool OUT_F32, bool BIAS_ROW>
__device__ __forceinline__ void gemm_core(
    u16b* __restrict__ As, u16b* __restrict__ Bs,   // As[2][128*64], Bs[2][BN*64]
    const u16b* __restrict__ A, const u16b* __restrict__ Bt,
    const float* __restrict__ bias, void* __restrict__ Cv,
    int N, int K, int bm, int bn, float oscale) {
  constexpr int NT = BN / 32;                  // n-tiles per wave
  constexpr int ASTRIDE = 128*64;
  constexpr int BSTRIDE = BN*64;
  const int tid = threadIdx.x;
  const int lane = tid & 63, wave = tid >> 6;
  const int wm = wave >> 1, wn = wave & 1;
  const int l15 = lane & 15, l4 = lane >> 4;
  float4v acc[4][NT];
#pragma unroll
  for (int i=0;i<4;++i)
#pragma unroll
    for (int j=0;j<NT;++j) acc[i][j] = (float4v){0.f,0.f,0.f,0.f};

  auto stage = [&](int buf, int k0) {
#pragma unroll
    for (int j=0;j<4;++j) {                    // As: 128 rows x 8 chunks
      int idx = j*256 + tid;
      int row = idx >> 3, seg = idx & 7;
      int segg = seg ^ (row & 7);
      gl_lds16(&A[(size_t)(bm+row)*K + k0 + segg*8], &As[buf*ASTRIDE + idx*8]);
    }
#pragma unroll
    for (int j=0;j<BN/32;++j) {                // Bs: BN rows x 8 chunks
      int idx = j*256 + tid;
      int row = idx >> 3, seg = idx & 7;
      int segg = seg ^ (row & 7);
      gl_lds16(&Bt[(size_t)(bn+row)*K + k0 + segg*8], &Bs[buf*BSTRIDE + idx*8]);
    }
  };

  const int NK = K >> 6;
  stage(0, 0);
  __syncthreads();                             // drain: buf0 ready
  for (int kt = 0; kt < NK; ++kt) {
    const int cur = kt & 1;
    if (kt + 1 < NK) stage(cur ^ 1, (kt + 1) << 6);   // issue next tile's loads
    const u16b* Asb = As + cur*ASTRIDE;
    const u16b* Bsb = Bs + cur*BSTRIDE;
#pragma unroll
    for (int ks=0; ks<2; ++ks) {
      short8v af[4], bf[NT];
      const int cs = ((ks*4 + l4) ^ (l15 & 7)) * 8;
#pragma unroll
      for (int mt=0;mt<4;++mt)
        af[mt] = *(const short8v*)&Asb[(wm*64+mt*16+l15)*64 + cs];
#pragma unroll
      for (int nt=0;nt<NT;++nt)
        bf[nt] = *(const short8v*)&Bsb[(wn*(BN/2)+nt*16+l15)*64 + cs];
#pragma unroll
      for (int mt=0;mt<4;++mt)
#pragma unroll
        for (int nt=0;nt<NT;++nt)
          acc[mt][nt] = __builtin_amdgcn_mfma_f32_16x16x32_bf16(af[mt], bf[nt], acc[mt][nt], 0, 0, 0);
    }
    __syncthreads();   // drains this wave's prefetch (vmcnt 0) + all LDS reads
  }

#pragma unroll
  for (int nt=0;nt<NT;++nt) {
    int col = bn + wn*(BN/2) + nt*16 + l15;
    float bbc = BIAS_ROW ? 0.f : bias[col];
#pragma unroll
    for (int mt=0;mt<4;++mt) {
      int row0 = bm + wm*64 + mt*16 + l4*4;
#pragma unroll
      for (int r=0;r<4;++r) {
        float bb = BIAS_ROW ? bias[row0+r] : bbc;
        float v = (acc[mt][nt][r] + bb) * oscale;  // C/D: col=l15, row=l4*4+r
        if (OUT_F32) ((float*)Cv)[(size_t)(row0+r)*N + col] = v;
        else         ((u16b*)Cv)[(size_t)(row0+r)*N + col] = f2bf(v);
      }
    }
  }
}

// final projection, fp32 out; flat grid 512, XCD-swizzled
__global__ __launch_bounds__(256) void gemm_out(
    const u16b* __restrict__ A, const u16b* __restrict__ Bt,
    const float* __restrict__ bias, float* __restrict__ C) {
  __shared__ __align__(16) u16b As[2*128*64];
  __shared__ __align__(16) u16b Bs[2*64*64];
  const int f = blockIdx.x;
  const int xcd = f & 7, s = f >> 3;
  const int bm = (xcd*4 + (s >> 4)) * 128;
  const int bn = (s & 15) * 64;
  gemm_core<64,true,false>(As, Bs, A, Bt, bias, C, 1024, 1024, bm, bn, 1.0f);
}

// ---------------- flash attention: 128 q x 128 kv, 32x32 MFMA, in-register P --------
// grid (32 bh, 16 qtile). 4 waves x 32 q. Static-max base-2 softmax (Q pre-scaled
// by 1/8*log2e in the Q-GEMM). Swapped QK^T via mfma_32x32x16(K,Q): lane holds
// S^T[kv][q=l&31] with kv=(r&3)+8(r>>2)+4hi per kv-block of 32 — which is exactly
// the mfma_32x32x8 A-frag layout (k=hi*4+j), so P never leaves registers.
// l accumulated in-lane (each lane's S values are all for its own q row);
// cross-half combine with one shfl_xor(32) at the end.
// LDS: Ks 16K + Vs 16K = 32768 B. VGPR-prefetch pipeline unchanged from R13.
__device__ __forceinline__ void attn_load(
    const u16b* __restrict__ Kgb, const u16b* __restrict__ Vtb,
    int kvoff, int tid, short8v kreg[4], short8v vreg[4]) {
#pragma unroll
  for (int j=0; j<4; ++j) {
    int idx = j*256 + tid;
    int rowk = idx >> 3, segk = idx & 7;
    kreg[j] = *(const short8v*)&Kgb[(size_t)(kvoff+rowk)*1024 + ((segk ^ (rowk & 7))*8)];
    int rowv = idx >> 4, segv = idx & 15;
    vreg[j] = *(const short8v*)&Vtb[(size_t)rowv*4096 + kvoff + ((segv ^ (rowv & 15))*8)];
  }
}

__global__ __launch_bounds__(256, 2) void attn_q128(
    const u16b* __restrict__ Q, const u16b* __restrict__ Kg,
    const u16b* __restrict__ Vt, u16b* __restrict__ O) {
  __shared__ __align__(16) u16b Ks[128*64];    // [kv][d]   chunk-swizzled (^row&7)
  __shared__ __align__(16) u16b Vs[64*128];    // [d][kv]   chunk-swizzled (^row&15)
  const int tid = threadIdx.x;
  const int lane = tid & 63, wave = tid >> 6;
  const int l31 = lane & 31, hi = lane >> 5;
  const int bh = blockIdx.x;
  const int b = bh >> 4, h = bh & 15;
  const int q0 = blockIdx.y * 128;
  const size_t seqbase = (size_t)b * 2048;
  const int colh = h * 64;
  const u16b* Kgb = Kg + seqbase*1024 + colh;
  const u16b* Vtb = Vt + (size_t)(h*64)*4096 + (size_t)b*2048;

  // prefetch tile 0 into registers
  short8v kreg[4], vreg[4];
  attn_load(Kgb, Vtb, 0, tid, kreg, vreg);

  // Q B-fragments for 32x32x16: lane holds Q[q=l31][d = ks*16 + hi*8 + j]
  short8v qf[4];
  {
    size_t qrow = seqbase + q0 + wave*32 + l31;
#pragma unroll
    for (int ks=0; ks<4; ++ks)
      qf[ks] = *(const short8v*)&Q[qrow*1024 + colh + ks*16 + hi*8];
  }

  float16v oacc[2];
#pragma unroll
  for (int nb=0; nb<2; ++nb)
#pragma unroll
    for (int r=0; r<16; ++r) oacc[nb][r] = 0.f;
  float lsum = 0.f;

  for (int kt = 0; kt < 16; ++kt) {
    // barrier A: all waves done reading Ks/Vs (iter kt-1)
    __syncthreads();
    // stage tile kt from registers (compiler waits the prefetch loads here)
#pragma unroll
    for (int j=0; j<4; ++j) {
      int idx = j*256 + tid;
      *(short8v*)&Ks[idx*8] = kreg[j];
      *(short8v*)&Vs[idx*8] = vreg[j];
    }
    // barrier B: writes visible block-wide
    __syncthreads();
    // prefetch tile kt+1 (in flight during compute kt; consumed at iter kt+1)
    if (kt < 15)
      attn_load(Kgb, Vtb, (kt+1)*128, tid, kreg, vreg);

    // ---- S^T = K·Q^T: sacc[kvblk] holds S^T[kv 32-block][q=l31] -------------
    float16v sacc[4];
#pragma unroll
    for (int kb=0; kb<4; ++kb)
#pragma unroll
      for (int r=0; r<16; ++r) sacc[kb][r] = 0.f;
    __builtin_amdgcn_s_setprio(1);
#pragma unroll
    for (int kb=0; kb<4; ++kb)
#pragma unroll
      for (int ks=0; ks<4; ++ks) {
        int row = kb*32 + l31;
        short8v kf = *(const short8v*)&Ks[row*64 + (((ks*2+hi) ^ (row & 7))*8)];
        sacc[kb] = __builtin_amdgcn_mfma_f32_32x32x16_bf16(kf, qf[ks], sacc[kb], 0, 0, 0);
      }
    __builtin_amdgcn_s_setprio(0);

    // ---- per kv-block: exp2 -> in-reg bf16 P -> PV (32x32x8, no exchange) ----
#pragma unroll
    for (int kb=0; kb<4; ++kb) {
      float e[16];
#pragma unroll
      for (int r=0; r<16; ++r) e[r] = exp2_fast(sacc[kb][r]);
#pragma unroll
      for (int r=0; r<16; ++r) lsum += e[r];
      unsigned int d[8];
#pragma unroll
      for (int i=0; i<8; ++i)   // pack hi16(e[2i]) | hi16(e[2i+1])<<16 (trunc bf16)
        d[i] = __builtin_amdgcn_perm(__float_as_uint(e[2*i+1]),
                                     __float_as_uint(e[2*i]), 0x07060302u);
      __builtin_amdgcn_s_setprio(1);
#pragma unroll
      for (int s=0; s<4; ++s) {   // kv sub-step of 8 within the 32-block
        union { unsigned int u[2]; short4v s4; } pu;
        pu.u[0] = d[2*s]; pu.u[1] = d[2*s+1];
        const short4v pf = pu.s4;  // A[q=l31][k=hi*4+j], kv = kb*32 + s*8 + k
#pragma unroll
        for (int nb=0; nb<2; ++nb) {
          int row = nb*32 + l31;   // V row = d
          short4v vf = *(const short4v*)&Vs[row*128 + (((kb*4+s) ^ (row & 15))*8) + hi*4];
          oacc[nb] = __builtin_amdgcn_mfma_f32_32x32x8bf16_1k(pf, vf, oacc[nb], 0, 0, 0);
        }
      }
      __builtin_amdgcn_s_setprio(0);
    }
  }

  // ---- epilogue: l[q] = own-half sum + partner-half sum; normalize, store ----
  float ltot = lsum + __shfl_xor(lsum, 32, 64);   // lane l holds l[q=l31]
#pragma unroll
  for (int r=0; r<16; ++r) {
    int qloc = (r & 3) + 8*(r >> 2) + 4*hi;       // oacc row -> q within wave tile
    float lv = __shfl(ltot, qloc, 64);
    float inv = 1.0f / lv;
    size_t row = seqbase + q0 + wave*32 + qloc;
    O[row*1024 + colh +      l31] = f2bf(oacc[0][r] * inv);
    O[row*1024 + colh + 32 + l31] = f2bf(oacc[1][r] * inv);
  }
}

extern "C" void kernel_launch(void* const* d_in, const int* in_sizes, int n_in,
                              void* d_out, int out_size, void* d_ws, size_t ws_size,
                              hipStream_t stream) {
  const float* x1 = (const float*)d_in[0];
  const float* x2 = (const float*)d_in[1];
  const float* Wq = (const float*)d_in[2];
  const float* bq = (const float*)d_in[3];
  const float* Wk = (const float*)d_in[4];
  const float* bk = (const float*)d_in[5];
  const float* Wv = (const float*)d_in[6];
  const float* bv = (const float*)d_in[7];
  const float* Wo = (const float*)d_in[8];
  const float* bo = (const float*)d_in[9];
  (void)in_sizes; (void)n_in; (void)out_size; (void)ws_size;

  u16b* ws = (u16b*)d_ws;
  const size_t Mi = 1024*1024;
  u16b* WT  = ws;               // WqT,WkT,WvT contiguous + WoT
  u16b* WoT = ws + 3*Mi;
  u16b* x1b = ws + 4*Mi;        // Cx aliases after Q-gemm consumed it
  u16b* x2b = ws + 8*Mi;
  u16b* QKV = ws + 12*Mi;       // Qb, Kb, Vtb (4Mi each) -> 48 MiB total
  u16b* Qb  = QKV;
  u16b* Kb  = QKV + 4*Mi;
  u16b* Vtb = QKV + 8*Mi;       // Vt[h*64+d][b*2048+kv], stride 4096
  u16b* Cx  = x1b;

  prep<<<dim3(1024,6), 256, 0, stream>>>(x1, x2, Wq, Wk, Wv, Wo, x1b, x2b, WT);

  gemm_qkv256<<<dim3(192), 512, 0, stream>>>(x1b, x2b, WT, bq, bk, bv, QKV);

  attn_q128<<<dim3(32,16), 256, 0, stream>>>(Qb, Kb, Vtb, Cx);

  gemm_out<<<dim3(512), 256, 0, stream>>>(Cx, WoT, bo, (float*)d_out);
}

// Round 5
// 202.942 us; speedup vs baseline: 1.0087x; 1.0087x over previous
//
#include <hip/hip_runtime.h>
#include <stdint.h>

// MultiHeadCrossAttention: B=2, SQ=SK=2048, D=1024, H=16, Dh=64, scale=1/8.
// fp32 in/out, bf16 MFMA internal.
// R15: fix R14's V-read bank conflict (6.29M conflict cycles, attn 49->55us).
//      Root cause: ds_read_b64 runs in 16-lane phases; all 16 lanes share hi and
//      row-stride 256B ≡ 0 mod bank-span -> 8 bank-pairs for 16 lanes (2-way).
//      Fix: Vs padded to [64][132] (row stride 264B = 66 dw ≡ 2 mod 32 -> bank
//      rotation 2/row). Reads hit 16 DISTINCT rows per phase -> bijective banks,
//      no swizzle needed. Staging remapped row-major (idx&63 = row) so write
//      phases also span 16 rows; V global read now strided (L2-resident, HBM 5%).
//      Single-variable change vs R14; K path and all other kernels untouched.
// R14: attn on 32x32 MFMAs, swapped QK^T, fully in-register P (no P LDS trip).
// R13/R12: gemm_qkv 256^2 4-quadrant-phase counted-vmcnt schedule.

typedef unsigned short u16b;
typedef __attribute__((ext_vector_type(4))) short short4v;
typedef __attribute__((ext_vector_type(8))) short short8v;
typedef __attribute__((ext_vector_type(4))) float float4v;
typedef __attribute__((ext_vector_type(16))) float float16v;
typedef __attribute__((ext_vector_type(2))) unsigned int uint2v;

#if __has_builtin(__builtin_amdgcn_exp2f)
__device__ __forceinline__ float exp2_fast(float x){ return __builtin_amdgcn_exp2f(x); }
#else
__device__ __forceinline__ float exp2_fast(float x){ return exp2f(x); }
#endif

__device__ __forceinline__ u16b f2bf(float f) {
  union { float f; unsigned int i; } v; v.f = f;
  return (u16b)((v.i + 0x7fffu + ((v.i >> 16) & 1u)) >> 16);  // RNE
}
__device__ __forceinline__ void gl_lds16(const u16b* g, u16b* l) {
  __builtin_amdgcn_global_load_lds(
      (const __attribute__((address_space(1))) void*)g,
      (__attribute__((address_space(3))) void*)l, 16, 0, 0);
}

#define FENCE_BARRIER() do { asm volatile("" ::: "memory"); \
  __builtin_amdgcn_s_barrier(); asm volatile("" ::: "memory"); } while(0)
#define LGKM0() do { asm volatile("s_waitcnt lgkmcnt(0)" ::: "memory"); \
  __builtin_amdgcn_sched_barrier(0); } while(0)
#define VMCNT(n) do { asm volatile("s_waitcnt vmcnt(" #n ")" ::: "memory"); \
  __builtin_amdgcn_sched_barrier(0); } while(0)

// ---------------- prep: y=0,1 -> cvt x1/x2 fp32->bf16 ; y=2..5 -> transpose W[y-2] ---
__global__ __launch_bounds__(256) void prep(
    const float* __restrict__ x1, const float* __restrict__ x2,
    const float* __restrict__ W0, const float* __restrict__ W1,
    const float* __restrict__ W2, const float* __restrict__ W3,
    u16b* __restrict__ x1b, u16b* __restrict__ x2b, u16b* __restrict__ WT) {
  const int tid = threadIdx.x;
  const int mode = blockIdx.y;
  if (mode < 2) {
    const float* src = mode ? x2 : x1;
    u16b* dst = mode ? x2b : x1b;
    const int n4 = 1024*1024;             // 4Mi elems / 4
    int i = blockIdx.x * 256 + tid;
    const int stride = gridDim.x * 256;
    for (; i < n4; i += stride) {
      float4v v = ((const float4v*)src)[i];
      short4v o;
      o[0]=(short)f2bf(v[0]); o[1]=(short)f2bf(v[1]);
      o[2]=(short)f2bf(v[2]); o[3]=(short)f2bf(v[3]);
      ((short4v*)dst)[i] = o;
    }
  } else {
    __shared__ u16b tile[32][33];
    const int z = mode - 2;
    const float* src = (z==0) ? W0 : (z==1) ? W1 : (z==2) ? W2 : W3;
    u16b* dst = WT + (size_t)z * (1024*1024);
    const int x = tid & 31, y = tid >> 5;   // 32 x 8
    const int bx = (blockIdx.x & 31) * 32, by = (blockIdx.x >> 5) * 32;
#pragma unroll
    for (int j=0;j<4;++j)
      tile[y*4+j][x] = f2bf(src[(size_t)(by + y*4+j)*1024 + bx + x]);
    __syncthreads();
#pragma unroll
    for (int j=0;j<4;++j)
      dst[(size_t)(bx + y*4+j)*1024 + by + x] = tile[x][y*4+j];
  }
}

// ---------------- 256x256 8-phase GEMM core (unchanged from R13) --------------------
template<bool BIAS_ROW>
__device__ __forceinline__ void gemm256_core(
    u16b* __restrict__ As, u16b* __restrict__ Bs,
    const u16b* __restrict__ A, const u16b* __restrict__ Bt,
    const float* __restrict__ bias, u16b* __restrict__ C,
    int N, int K, int bm, int bn, float oscale) {
  constexpr int ASTR = 256*64, BSTR = 256*64;
  const int tid = threadIdx.x;
  const int lane = tid & 63, wave = tid >> 6;
  const int wr = wave >> 2, wc = wave & 3;      // 2x4 waves in a quadrant
  const int l15 = lane & 15, l4 = lane >> 4;

  auto stage_half = [&](const u16b* __restrict__ G, int row0, int k0,
                        u16b* __restrict__ Lbase) {
#pragma unroll
    for (int j=0;j<2;++j) {                     // 128 rows x 8 chunks, 2 loads/thr
      int idx = j*512 + tid;
      int row = idx >> 3, seg = idx & 7;
      int segg = seg ^ (row & 7);
      gl_lds16(&G[(size_t)(row0+row)*K + k0 + segg*8], &Lbase[idx*8]);
    }
  };

  float4v acc[2][2][4][2];
#pragma unroll
  for (int qm=0;qm<2;++qm)
#pragma unroll
  for (int qn=0;qn<2;++qn)
#pragma unroll
  for (int m=0;m<4;++m)
#pragma unroll
  for (int n=0;n<2;++n) acc[qm][qn][m][n] = (float4v){0.f,0.f,0.f,0.f};

  const int NK = K >> 6;
  // ---- prologue: tile0 all 4 halves + tile1 A0,B0 (12 loads/thr) --------------
  stage_half(A,  bm+0,   0,  As + 0);           // t0:A0
  stage_half(Bt, bn+0,   0,  Bs + 0);           // t0:B0
  stage_half(A,  bm+128, 0,  As + 128*64);      // t0:A1
  stage_half(Bt, bn+128, 0,  Bs + 128*64);      // t0:B1
  stage_half(A,  bm+0,   64, As + ASTR);        // t1:A0
  stage_half(Bt, bn+0,   64, Bs + BSTR);        // t1:B0
  VMCNT(4);                                     // t0 fully landed; t1:A0,B0 in flight
  FENCE_BARRIER();

  int cur = 0;
  for (int t = 0; t < NK; ++t) {
    u16b* Ac = As + cur*ASTR;  u16b* Bc = Bs + cur*BSTR;
    u16b* An = As + (cur^1)*ASTR;  u16b* Bn = Bs + (cur^1)*BSTR;
    const int k1 = (t+1) << 6, k2 = (t+2) << 6;
    short8v af[4][2], bf0[2][2], bf1[2][2];

    // ---- ph1: quad (0,0). reads A0 + B0; stage (t+1):A1 -> next buf ----------
#pragma unroll
    for (int m=0;m<4;++m)
#pragma unroll
      for (int ks=0;ks<2;++ks)
        af[m][ks] = *(const short8v*)&Ac[(0*128 + wr*64 + m*16 + l15)*64
                                         + (((ks*4+l4) ^ (l15&7))*8)];
#pragma unroll
    for (int n=0;n<2;++n)
#pragma unroll
      for (int ks=0;ks<2;++ks)
        bf0[n][ks] = *(const short8v*)&Bc[(0*128 + wc*32 + n*16 + l15)*64
                                          + (((ks*4+l4) ^ (l15&7))*8)];
    if (t+1 < NK) stage_half(A, bm+128, k1, An + 128*64);
    FENCE_BARRIER();
    LGKM0();
    __builtin_amdgcn_s_setprio(1);
#pragma unroll
    for (int m=0;m<4;++m)
#pragma unroll
      for (int n=0;n<2;++n)
#pragma unroll
        for (int ks=0;ks<2;++ks)
          acc[0][0][m][n] = __builtin_amdgcn_mfma_f32_16x16x32_bf16(
              af[m][ks], bf0[n][ks], acc[0][0][m][n], 0, 0, 0);
    __builtin_amdgcn_s_setprio(0);
    FENCE_BARRIER();

    // ---- ph2: quad (0,1). reads B1 (af reused); stage (t+1):B1 -> next buf ---
#pragma unroll
    for (int n=0;n<2;++n)
#pragma unroll
      for (int ks=0;ks<2;++ks)
        bf1[n][ks] = *(const short8v*)&Bc[(1*128 + wc*32 + n*16 + l15)*64
                                          + (((ks*4+l4) ^ (l15&7))*8)];
    if (t+1 < NK) stage_half(Bt, bn+128, k1, Bn + 128*64);
    FENCE_BARRIER();
    LGKM0();
    __builtin_amdgcn_s_setprio(1);
#pragma unroll
    for (int m=0;m<4;++m)
#pragma unroll
      for (int n=0;n<2;++n)
#pragma unroll
        for (int ks=0;ks<2;++ks)
          acc[0][1][m][n] = __builtin_amdgcn_mfma_f32_16x16x32_bf16(
              af[m][ks], bf1[n][ks], acc[0][1][m][n], 0, 0, 0);
    __builtin_amdgcn_s_setprio(0);
    FENCE_BARRIER();

    // ---- ph3: quad (1,0). reads A1 (bf0 from regs); stage (t+2):A0 -> cur.A0 -
#pragma unroll
    for (int m=0;m<4;++m)
#pragma unroll
      for (int ks=0;ks<2;++ks)
        af[m][ks] = *(const short8v*)&Ac[(1*128 + wr*64 + m*16 + l15)*64
                                         + (((ks*4+l4) ^ (l15&7))*8)];
    if (t+2 < NK) stage_half(A, bm+0, k2, Ac + 0);
    FENCE_BARRIER();
    LGKM0();
    __builtin_amdgcn_s_setprio(1);
#pragma unroll
    for (int m=0;m<4;++m)
#pragma unroll
      for (int n=0;n<2;++n)
#pragma unroll
        for (int ks=0;ks<2;++ks)
          acc[1][0][m][n] = __builtin_amdgcn_mfma_f32_16x16x32_bf16(
              af[m][ks], bf0[n][ks], acc[1][0][m][n], 0, 0, 0);
    __builtin_amdgcn_s_setprio(0);
    FENCE_BARRIER();

    // ---- ph4: quad (1,1). all operands in regs; stage (t+2):B0 -> cur.B0 -----
    if (t+2 < NK) stage_half(Bt, bn+0, k2, Bc + 0);
    FENCE_BARRIER();
    LGKM0();
    __builtin_amdgcn_s_setprio(1);
#pragma unroll
    for (int m=0;m<4;++m)
#pragma unroll
      for (int n=0;n<2;++n)
#pragma unroll
        for (int ks=0;ks<2;++ks)
          acc[1][1][m][n] = __builtin_amdgcn_mfma_f32_16x16x32_bf16(
              af[m][ks], bf1[n][ks], acc[1][1][m][n], 0, 0, 0);
    __builtin_amdgcn_s_setprio(0);
    if (t == NK-2) { VMCNT(0); }                 // tail: next tile has nothing newer
    else          { VMCNT(4); }                  // tile t+1 fully landed; 2 halves fly
    FENCE_BARRIER();
    cur ^= 1;
  }

  // ---- epilogue ---------------------------------------------------------------
#pragma unroll
  for (int qm=0;qm<2;++qm)
#pragma unroll
  for (int qn=0;qn<2;++qn)
#pragma unroll
  for (int n=0;n<2;++n) {
    int col = bn + qn*128 + wc*32 + n*16 + l15;
    float bbc = BIAS_ROW ? 0.f : bias[col];
#pragma unroll
    for (int m=0;m<4;++m) {
      int row0 = bm + qm*128 + wr*64 + m*16 + l4*4;
#pragma unroll
      for (int r=0;r<4;++r) {
        float bb = BIAS_ROW ? bias[row0+r] : bbc;
        float v = (acc[qm][qn][m][n][r] + bb) * oscale;
        C[(size_t)(row0+r)*N + col] = f2bf(v);
      }
    }
  }
}

// Q / K / V^T projections, 192 blocks x 512 threads, per-z XCD-chunked swizzle.
__global__ __launch_bounds__(512, 2) void gemm_qkv256(
    const u16b* __restrict__ x1b, const u16b* __restrict__ x2b,
    const u16b* __restrict__ WT, const float* __restrict__ bq,
    const float* __restrict__ bk, const float* __restrict__ bv,
    u16b* __restrict__ QKV) {
  __shared__ __align__(16) u16b As[2*256*64];
  __shared__ __align__(16) u16b Bs[2*256*64];
  const int f = blockIdx.x;
  const int z = f >> 6;                      // 0=Q, 1=K, 2=V^T
  const int u = f & 63;
  const int w = ((u & 7) << 3) | (u >> 3);   // xcd = u&7 gets 8 contiguous tiles
  const size_t Mi = 1024*1024;
  const float QSCALE = 0.125f * 1.4426950408889634f;   // 1/sqrt(Dh) * log2(e)
  if (z == 2) {
    int bm = (w >> 4) * 256;                 // WvT rows (d)
    int bn = (w & 15) * 256;                 // tokens
    gemm256_core<true>(As, Bs, WT + 2*Mi, x2b, bv, QKV + 8*Mi,
                       4096, 1024, bm, bn, 1.0f);
  } else {
    int bm = (w >> 2) * 256;                 // tokens
    int bn = (w & 3) * 256;                  // d_model cols
    gemm256_core<false>(As, Bs, z ? x2b : x1b, WT + (size_t)z*Mi,
                        z ? bk : bq, QKV + (size_t)z*4*Mi,
                        1024, 1024, bm, bn, z ? 1.0f : QSCALE);
  }
}

// ---------------- 128-tile GEMM core (gemm_out): 2-phase dbuf pipeline --------------
template<int BN, bool OUT_F32, bool BIAS_ROW>
__device__ __forceinline__ void gemm_core(
    u16b* __restrict__ As, u16b* __restrict__ Bs,   // As[2][128*64], Bs[2][BN*64]
    const u16b* __restrict__ A, const u16b* __restrict__ Bt,
    const float* __restrict__ bias, void* __restrict__ Cv,
    int N, int K, int bm, int bn, float oscale) {
  constexpr int NT = BN / 32;                  // n-tiles per wave
  constexpr int ASTRIDE = 128*64;
  constexpr int BSTRIDE = BN*64;
  const int tid = threadIdx.x;
  const int lane = tid & 63, wave = tid >> 6;
  const int wm = wave >> 1, wn = wave & 1;
  const int l15 = lane & 15, l4 = lane >> 4;
  float4v acc[4][NT];
#pragma unroll
  for (int i=0;i<4;++i)
#pragma unroll
    for (int j=0;j<NT;++j) acc[i][j] = (float4v){0.f,0.f,0.f,0.f};

  auto stage = [&](int buf, int k0) {
#pragma unroll
    for (int j=0;j<4;++j) {                    // As: 128 rows x 8 chunks
      int idx = j*256 + tid;
      int row = idx >> 3, seg = idx & 7;
      int segg = seg ^ (row & 7);
      gl_lds16(&A[(size_t)(bm+row)*K + k0 + segg*8], &As[buf*ASTRIDE + idx*8]);
    }
#pragma unroll
    for (int j=0;j<BN/32;++j) {                // Bs: BN rows x 8 chunks
      int idx = j*256 + tid;
      int row = idx >> 3, seg = idx & 7;
      int segg = seg ^ (row & 7);
      gl_lds16(&Bt[(size_t)(bn+row)*K + k0 + segg*8], &Bs[buf*BSTRIDE + idx*8]);
    }
  };

  const int NK = K >> 6;
  stage(0, 0);
  __syncthreads();                             // drain: buf0 ready
  for (int kt = 0; kt < NK; ++kt) {
    const int cur = kt & 1;
    if (kt + 1 < NK) stage(cur ^ 1, (kt + 1) << 6);   // issue next tile's loads
    const u16b* Asb = As + cur*ASTRIDE;
    const u16b* Bsb = Bs + cur*BSTRIDE;
#pragma unroll
    for (int ks=0; ks<2; ++ks) {
      short8v af[4], bf[NT];
      const int cs = ((ks*4 + l4) ^ (l15 & 7)) * 8;
#pragma unroll
      for (int mt=0;mt<4;++mt)
        af[mt] = *(const short8v*)&Asb[(wm*64+mt*16+l15)*64 + cs];
#pragma unroll
      for (int nt=0;nt<NT;++nt)
        bf[nt] = *(const short8v*)&Bsb[(wn*(BN/2)+nt*16+l15)*64 + cs];
#pragma unroll
      for (int mt=0;mt<4;++mt)
#pragma unroll
        for (int nt=0;nt<NT;++nt)
          acc[mt][nt] = __builtin_amdgcn_mfma_f32_16x16x32_bf16(af[mt], bf[nt], acc[mt][nt], 0, 0, 0);
    }
    __syncthreads();   // drains this wave's prefetch (vmcnt 0) + all LDS reads
  }

#pragma unroll
  for (int nt=0;nt<NT;++nt) {
    int col = bn + wn*(BN/2) + nt*16 + l15;
    float bbc = BIAS_ROW ? 0.f : bias[col];
#pragma unroll
    for (int mt=0;mt<4;++mt) {
      int row0 = bm + wm*64 + mt*16 + l4*4;
#pragma unroll
      for (int r=0;r<4;++r) {
        float bb = BIAS_ROW ? bias[row0+r] : bbc;
        float v = (acc[mt][nt][r] + bb) * oscale;  // C/D: col=l15, row=l4*4+r
        if (OUT_F32) ((float*)Cv)[(size_t)(row0+r)*N + col] = v;
        else         ((u16b*)Cv)[(size_t)(row0+r)*N + col] = f2bf(v);
      }
    }
  }
}

// final projection, fp32 out; flat grid 512, XCD-swizzled
__global__ __launch_bounds__(256) void gemm_out(
    const u16b* __restrict__ A, const u16b* __restrict__ Bt,
    const float* __restrict__ bias, float* __restrict__ C) {
  __shared__ __align__(16) u16b As[2*128*64];
  __shared__ __align__(16) u16b Bs[2*64*64];
  const int f = blockIdx.x;
  const int xcd = f & 7, s = f >> 3;
  const int bm = (xcd*4 + (s >> 4)) * 128;
  const int bn = (s & 15) * 64;
  gemm_core<64,true,false>(As, Bs, A, Bt, bias, C, 1024, 1024, bm, bn, 1.0f);
}

// ---------------- flash attention: 128 q x 128 kv, 32x32 MFMA, in-register P --------
// grid (32 bh, 16 qtile). 4 waves x 32 q. Swapped QK^T via mfma_32x32x16(K,Q):
// lane holds S^T[kv][q=l31] at kv=(r&3)+8(r>>2)+4hi per 32-kv block — exactly the
// mfma_32x32x8 A-frag layout (k=hi*4+j): P never leaves registers.
// Vs layout (R15): [64][132] u16, +8B row pad -> row stride 66 dwords ≡ 2 mod 32.
// b64 reads hit 16 distinct rows per phase -> banks 2*l31+c, bijective, NO swizzle.
// Staging V: row-major mapping (idx&63=row) so b64 write phases also span 16 rows.
// LDS: Ks 16384 + Vs 16896 = 33280 B.
__device__ __forceinline__ void attn_load(
    const u16b* __restrict__ Kgb, const u16b* __restrict__ Vtb,
    int kvoff, int tid, short8v kreg[4], short8v vreg[4]) {
#pragma unroll
  for (int j=0; j<4; ++j) {
    int idx = j*256 + tid;
    int rowk = idx >> 3, segk = idx & 7;
    kreg[j] = *(const short8v*)&Kgb[(size_t)(kvoff+rowk)*1024 + ((segk ^ (rowk & 7))*8)];
    int rowv = idx & 63, segv = idx >> 6;   // row-major: 16-lane groups span 16 rows
    vreg[j] = *(const short8v*)&Vtb[(size_t)rowv*4096 + kvoff + segv*8];
  }
}

__global__ __launch_bounds__(256, 2) void attn_q128(
    const u16b* __restrict__ Q, const u16b* __restrict__ Kg,
    const u16b* __restrict__ Vt, u16b* __restrict__ O) {
  __shared__ __align__(16) u16b Ks[128*64];    // [kv][d]  chunk-swizzled (^row&7)
  __shared__ __align__(16) u16b Vs[64*132];    // [d][kv]  +8B row pad, linear cols
  const int tid = threadIdx.x;
  const int lane = tid & 63, wave = tid >> 6;
  const int l31 = lane & 31, hi = lane >> 5;
  const int bh = blockIdx.x;
  const int b = bh >> 4, h = bh & 15;
  const int q0 = blockIdx.y * 128;
  const size_t seqbase = (size_t)b * 2048;
  const int colh = h * 64;
  const u16b* Kgb = Kg + seqbase*1024 + colh;
  const u16b* Vtb = Vt + (size_t)(h*64)*4096 + (size_t)b*2048;

  // prefetch tile 0 into registers
  short8v kreg[4], vreg[4];
  attn_load(Kgb, Vtb, 0, tid, kreg, vreg);

  // Q B-fragments for 32x32x16: lane holds Q[q=l31][d = ks*16 + hi*8 + j]
  short8v qf[4];
  {
    size_t qrow = seqbase + q0 + wave*32 + l31;
#pragma unroll
    for (int ks=0; ks<4; ++ks)
      qf[ks] = *(const short8v*)&Q[qrow*1024 + colh + ks*16 + hi*8];
  }

  float16v oacc[2];
#pragma unroll
  for (int nb=0; nb<2; ++nb)
#pragma unroll
    for (int r=0; r<16; ++r) oacc[nb][r] = 0.f;
  float lsum = 0.f;

  for (int kt = 0; kt < 16; ++kt) {
    // barrier A: all waves done reading Ks/Vs (iter kt-1)
    __syncthreads();
    // stage tile kt from registers (compiler waits the prefetch loads here)
#pragma unroll
    for (int j=0; j<4; ++j) {
      int idx = j*256 + tid;
      *(short8v*)&Ks[idx*8] = kreg[j];
      int rowv = idx & 63, segv = idx >> 6;
      union { short8v s; uint2v u[2]; } tv; tv.s = vreg[j];
      *(uint2v*)&Vs[rowv*132 + segv*8]     = tv.u[0];
      *(uint2v*)&Vs[rowv*132 + segv*8 + 4] = tv.u[1];
    }
    // barrier B: writes visible block-wide
    __syncthreads();
    // prefetch tile kt+1 (in flight during compute kt; consumed at iter kt+1)
    if (kt < 15)
      attn_load(Kgb, Vtb, (kt+1)*128, tid, kreg, vreg);

    // ---- S^T = K·Q^T: sacc[kvblk] holds S^T[kv 32-block][q=l31] -------------
    float16v sacc[4];
#pragma unroll
    for (int kb=0; kb<4; ++kb)
#pragma unroll
      for (int r=0; r<16; ++r) sacc[kb][r] = 0.f;
    __builtin_amdgcn_s_setprio(1);
#pragma unroll
    for (int kb=0; kb<4; ++kb)
#pragma unroll
      for (int ks=0; ks<4; ++ks) {
        int row = kb*32 + l31;
        short8v kf = *(const short8v*)&Ks[row*64 + (((ks*2+hi) ^ (row & 7))*8)];
        sacc[kb] = __builtin_amdgcn_mfma_f32_32x32x16_bf16(kf, qf[ks], sacc[kb], 0, 0, 0);
      }
    __builtin_amdgcn_s_setprio(0);

    // ---- per kv-block: exp2 -> in-reg bf16 P -> PV (32x32x8, no exchange) ----
#pragma unroll
    for (int kb=0; kb<4; ++kb) {
      float e[16];
#pragma unroll
      for (int r=0; r<16; ++r) e[r] = exp2_fast(sacc[kb][r]);
#pragma unroll
      for (int r=0; r<16; ++r) lsum += e[r];
      unsigned int d[8];
#pragma unroll
      for (int i=0; i<8; ++i)   // pack hi16(e[2i]) | hi16(e[2i+1])<<16 (trunc bf16)
        d[i] = __builtin_amdgcn_perm(__float_as_uint(e[2*i+1]),
                                     __float_as_uint(e[2*i]), 0x07060302u);
      __builtin_amdgcn_s_setprio(1);
#pragma unroll
      for (int s=0; s<4; ++s) {   // kv sub-step of 8 within the 32-block
        union { unsigned int u[2]; short4v s4; } pu;
        pu.u[0] = d[2*s]; pu.u[1] = d[2*s+1];
        const short4v pf = pu.s4;  // A[q=l31][k=hi*4+j], kv = kb*32 + s*8 + k
#pragma unroll
        for (int nb=0; nb<2; ++nb) {
          int row = nb*32 + l31;   // V row = d
          short4v vf = *(const short4v*)&Vs[row*132 + kb*32 + s*8 + hi*4];
          oacc[nb] = __builtin_amdgcn_mfma_f32_32x32x8bf16_1k(pf, vf, oacc[nb], 0, 0, 0);
        }
      }
      __builtin_amdgcn_s_setprio(0);
    }
  }

  // ---- epilogue: l[q] = own-half sum + partner-half sum; normalize, store ----
  float ltot = lsum + __shfl_xor(lsum, 32, 64);   // lane l holds l[q=l31]
#pragma unroll
  for (int r=0; r<16; ++r) {
    int qloc = (r & 3) + 8*(r >> 2) + 4*hi;       // oacc row -> q within wave tile
    float lv = __shfl(ltot, qloc, 64);
    float inv = 1.0f / lv;
    size_t row = seqbase + q0 + wave*32 + qloc;
    O[row*1024 + colh +      l31] = f2bf(oacc[0][r] * inv);
    O[row*1024 + colh + 32 + l31] = f2bf(oacc[1][r] * inv);
  }
}

extern "C" void kernel_launch(void* const* d_in, const int* in_sizes, int n_in,
                              void* d_out, int out_size, void* d_ws, size_t ws_size,
                              hipStream_t stream) {
  const float* x1 = (const float*)d_in[0];
  const float* x2 = (const float*)d_in[1];
  const float* Wq = (const float*)d_in[2];
  const float* bq = (const float*)d_in[3];
  const float* Wk = (const float*)d_in[4];
  const float* bk = (const float*)d_in[5];
  const float* Wv = (const float*)d_in[6];
  const float* bv = (const float*)d_in[7];
  const float* Wo = (const float*)d_in[8];
  const float* bo = (const float*)d_in[9];
  (void)in_sizes; (void)n_in; (void)out_size; (void)ws_size;

  u16b* ws = (u16b*)d_ws;
  const size_t Mi = 1024*1024;
  u16b* WT  = ws;               // WqT,WkT,WvT contiguous + WoT
  u16b* WoT = ws + 3*Mi;
  u16b* x1b = ws + 4*Mi;        // Cx aliases after Q-gemm consumed it
  u16b* x2b = ws + 8*Mi;
  u16b* QKV = ws + 12*Mi;       // Qb, Kb, Vtb (4Mi each) -> 48 MiB total
  u16b* Qb  = QKV;
  u16b* Kb  = QKV + 4*Mi;
  u16b* Vtb = QKV + 8*Mi;       // Vt[h*64+d][b*2048+kv], stride 4096
  u16b* Cx  = x1b;

  prep<<<dim3(1024,6), 256, 0, stream>>>(x1, x2, Wq, Wk, Wv, Wo, x1b, x2b, WT);

  gemm_qkv256<<<dim3(192), 512, 0, stream>>>(x1b, x2b, WT, bq, bk, bv, QKV);

  attn_q128<<<dim3(32,16), 256, 0, stream>>>(Qb, Kb, Vtb, Cx);

  gemm_out<<<dim3(512), 256, 0, stream>>>(Cx, WoT, bo, (float*)d_out);
}

// Round 6
// 197.426 us; speedup vs baseline: 1.0369x; 1.0279x over previous
//
#include <hip/hip_runtime.h>
#include <stdint.h>

// MultiHeadCrossAttention: B=2, SQ=SK=2048, D=1024, H=16, Dh=64, scale=1/8.
// fp32 in/out, bf16 MFMA internal.
// R16: two attn fixes from R15's null (conflicts 6.3M->2.1M, time unchanged ->
//      conflicts were not binding; MFMA-busy 14.8->20.1us vs R13 with FEWER
//      useful FLOPs -> 32x32x8bf16_1k is HALF-RATE (8cyc/16kFLOP)).
//      (a) PV now mfma_f32_32x32x16 with a kv->k PERMUTATION chosen so each
//          lane's A-frag is exactly its packed d[0..3]/d[4..7] registers
//          (no cross-lane exchange, no repack): mu0 = [0-3,8-11|4-7,12-15],
//          mu1 = +16. B-frag = two b64 reads/op from Vs at matching kv sets.
//          16 full-rate PV MFMAs/kt instead of 32 half-rate.
//      (b) K/V LDS double-buffered; ONE barrier per kt (was 2): write tile
//          kt+1 -> buf^1 at end of iter kt (its last readers finished before
//          barrier(kt)); prefetch loads get the full compute phase to land.
// R15: Vs[64][132] row-pad (b64 read phases hit 16 distinct rows, stride ≡2
//      mod 32 dwords -> bijective banks). R14: swapped QK^T, in-register P.
// R13/R12: gemm_qkv 256^2 4-quadrant-phase counted-vmcnt schedule.

typedef unsigned short u16b;
typedef __attribute__((ext_vector_type(4))) short short4v;
typedef __attribute__((ext_vector_type(8))) short short8v;
typedef __attribute__((ext_vector_type(4))) float float4v;
typedef __attribute__((ext_vector_type(16))) float float16v;
typedef __attribute__((ext_vector_type(2))) unsigned int uint2v;

#if __has_builtin(__builtin_amdgcn_exp2f)
__device__ __forceinline__ float exp2_fast(float x){ return __builtin_amdgcn_exp2f(x); }
#else
__device__ __forceinline__ float exp2_fast(float x){ return exp2f(x); }
#endif

__device__ __forceinline__ u16b f2bf(float f) {
  union { float f; unsigned int i; } v; v.f = f;
  return (u16b)((v.i + 0x7fffu + ((v.i >> 16) & 1u)) >> 16);  // RNE
}
__device__ __forceinline__ void gl_lds16(const u16b* g, u16b* l) {
  __builtin_amdgcn_global_load_lds(
      (const __attribute__((address_space(1))) void*)g,
      (__attribute__((address_space(3))) void*)l, 16, 0, 0);
}

#define FENCE_BARRIER() do { asm volatile("" ::: "memory"); \
  __builtin_amdgcn_s_barrier(); asm volatile("" ::: "memory"); } while(0)
#define LGKM0() do { asm volatile("s_waitcnt lgkmcnt(0)" ::: "memory"); \
  __builtin_amdgcn_sched_barrier(0); } while(0)
#define VMCNT(n) do { asm volatile("s_waitcnt vmcnt(" #n ")" ::: "memory"); \
  __builtin_amdgcn_sched_barrier(0); } while(0)

// ---------------- prep: y=0,1 -> cvt x1/x2 fp32->bf16 ; y=2..5 -> transpose W[y-2] ---
__global__ __launch_bounds__(256) void prep(
    const float* __restrict__ x1, const float* __restrict__ x2,
    const float* __restrict__ W0, const float* __restrict__ W1,
    const float* __restrict__ W2, const float* __restrict__ W3,
    u16b* __restrict__ x1b, u16b* __restrict__ x2b, u16b* __restrict__ WT) {
  const int tid = threadIdx.x;
  const int mode = blockIdx.y;
  if (mode < 2) {
    const float* src = mode ? x2 : x1;
    u16b* dst = mode ? x2b : x1b;
    const int n4 = 1024*1024;             // 4Mi elems / 4
    int i = blockIdx.x * 256 + tid;
    const int stride = gridDim.x * 256;
    for (; i < n4; i += stride) {
      float4v v = ((const float4v*)src)[i];
      short4v o;
      o[0]=(short)f2bf(v[0]); o[1]=(short)f2bf(v[1]);
      o[2]=(short)f2bf(v[2]); o[3]=(short)f2bf(v[3]);
      ((short4v*)dst)[i] = o;
    }
  } else {
    __shared__ u16b tile[32][33];
    const int z = mode - 2;
    const float* src = (z==0) ? W0 : (z==1) ? W1 : (z==2) ? W2 : W3;
    u16b* dst = WT + (size_t)z * (1024*1024);
    const int x = tid & 31, y = tid >> 5;   // 32 x 8
    const int bx = (blockIdx.x & 31) * 32, by = (blockIdx.x >> 5) * 32;
#pragma unroll
    for (int j=0;j<4;++j)
      tile[y*4+j][x] = f2bf(src[(size_t)(by + y*4+j)*1024 + bx + x]);
    __syncthreads();
#pragma unroll
    for (int j=0;j<4;++j)
      dst[(size_t)(bx + y*4+j)*1024 + by + x] = tile[x][y*4+j];
  }
}

// ---------------- 256x256 8-phase GEMM core (unchanged from R13) --------------------
template<bool BIAS_ROW>
__device__ __forceinline__ void gemm256_core(
    u16b* __restrict__ As, u16b* __restrict__ Bs,
    const u16b* __restrict__ A, const u16b* __restrict__ Bt,
    const float* __restrict__ bias, u16b* __restrict__ C,
    int N, int K, int bm, int bn, float oscale) {
  constexpr int ASTR = 256*64, BSTR = 256*64;
  const int tid = threadIdx.x;
  const int lane = tid & 63, wave = tid >> 6;
  const int wr = wave >> 2, wc = wave & 3;      // 2x4 waves in a quadrant
  const int l15 = lane & 15, l4 = lane >> 4;

  auto stage_half = [&](const u16b* __restrict__ G, int row0, int k0,
                        u16b* __restrict__ Lbase) {
#pragma unroll
    for (int j=0;j<2;++j) {                     // 128 rows x 8 chunks, 2 loads/thr
      int idx = j*512 + tid;
      int row = idx >> 3, seg = idx & 7;
      int segg = seg ^ (row & 7);
      gl_lds16(&G[(size_t)(row0+row)*K + k0 + segg*8], &Lbase[idx*8]);
    }
  };

  float4v acc[2][2][4][2];
#pragma unroll
  for (int qm=0;qm<2;++qm)
#pragma unroll
  for (int qn=0;qn<2;++qn)
#pragma unroll
  for (int m=0;m<4;++m)
#pragma unroll
  for (int n=0;n<2;++n) acc[qm][qn][m][n] = (float4v){0.f,0.f,0.f,0.f};

  const int NK = K >> 6;
  // ---- prologue: tile0 all 4 halves + tile1 A0,B0 (12 loads/thr) --------------
  stage_half(A,  bm+0,   0,  As + 0);           // t0:A0
  stage_half(Bt, bn+0,   0,  Bs + 0);           // t0:B0
  stage_half(A,  bm+128, 0,  As + 128*64);      // t0:A1
  stage_half(Bt, bn+128, 0,  Bs + 128*64);      // t0:B1
  stage_half(A,  bm+0,   64, As + ASTR);        // t1:A0
  stage_half(Bt, bn+0,   64, Bs + BSTR);        // t1:B0
  VMCNT(4);                                     // t0 fully landed; t1:A0,B0 in flight
  FENCE_BARRIER();

  int cur = 0;
  for (int t = 0; t < NK; ++t) {
    u16b* Ac = As + cur*ASTR;  u16b* Bc = Bs + cur*BSTR;
    u16b* An = As + (cur^1)*ASTR;  u16b* Bn = Bs + (cur^1)*BSTR;
    const int k1 = (t+1) << 6, k2 = (t+2) << 6;
    short8v af[4][2], bf0[2][2], bf1[2][2];

    // ---- ph1: quad (0,0). reads A0 + B0; stage (t+1):A1 -> next buf ----------
#pragma unroll
    for (int m=0;m<4;++m)
#pragma unroll
      for (int ks=0;ks<2;++ks)
        af[m][ks] = *(const short8v*)&Ac[(0*128 + wr*64 + m*16 + l15)*64
                                         + (((ks*4+l4) ^ (l15&7))*8)];
#pragma unroll
    for (int n=0;n<2;++n)
#pragma unroll
      for (int ks=0;ks<2;++ks)
        bf0[n][ks] = *(const short8v*)&Bc[(0*128 + wc*32 + n*16 + l15)*64
                                          + (((ks*4+l4) ^ (l15&7))*8)];
    if (t+1 < NK) stage_half(A, bm+128, k1, An + 128*64);
    FENCE_BARRIER();
    LGKM0();
    __builtin_amdgcn_s_setprio(1);
#pragma unroll
    for (int m=0;m<4;++m)
#pragma unroll
      for (int n=0;n<2;++n)
#pragma unroll
        for (int ks=0;ks<2;++ks)
          acc[0][0][m][n] = __builtin_amdgcn_mfma_f32_16x16x32_bf16(
              af[m][ks], bf0[n][ks], acc[0][0][m][n], 0, 0, 0);
    __builtin_amdgcn_s_setprio(0);
    FENCE_BARRIER();

    // ---- ph2: quad (0,1). reads B1 (af reused); stage (t+1):B1 -> next buf ---
#pragma unroll
    for (int n=0;n<2;++n)
#pragma unroll
      for (int ks=0;ks<2;++ks)
        bf1[n][ks] = *(const short8v*)&Bc[(1*128 + wc*32 + n*16 + l15)*64
                                          + (((ks*4+l4) ^ (l15&7))*8)];
    if (t+1 < NK) stage_half(Bt, bn+128, k1, Bn + 128*64);
    FENCE_BARRIER();
    LGKM0();
    __builtin_amdgcn_s_setprio(1);
#pragma unroll
    for (int m=0;m<4;++m)
#pragma unroll
      for (int n=0;n<2;++n)
#pragma unroll
        for (int ks=0;ks<2;++ks)
          acc[0][1][m][n] = __builtin_amdgcn_mfma_f32_16x16x32_bf16(
              af[m][ks], bf1[n][ks], acc[0][1][m][n], 0, 0, 0);
    __builtin_amdgcn_s_setprio(0);
    FENCE_BARRIER();

    // ---- ph3: quad (1,0). reads A1 (bf0 from regs); stage (t+2):A0 -> cur.A0 -
#pragma unroll
    for (int m=0;m<4;++m)
#pragma unroll
      for (int ks=0;ks<2;++ks)
        af[m][ks] = *(const short8v*)&Ac[(1*128 + wr*64 + m*16 + l15)*64
                                         + (((ks*4+l4) ^ (l15&7))*8)];
    if (t+2 < NK) stage_half(A, bm+0, k2, Ac + 0);
    FENCE_BARRIER();
    LGKM0();
    __builtin_amdgcn_s_setprio(1);
#pragma unroll
    for (int m=0;m<4;++m)
#pragma unroll
      for (int n=0;n<2;++n)
#pragma unroll
        for (int ks=0;ks<2;++ks)
          acc[1][0][m][n] = __builtin_amdgcn_mfma_f32_16x16x32_bf16(
              af[m][ks], bf0[n][ks], acc[1][0][m][n], 0, 0, 0);
    __builtin_amdgcn_s_setprio(0);
    FENCE_BARRIER();

    // ---- ph4: quad (1,1). all operands in regs; stage (t+2):B0 -> cur.B0 -----
    if (t+2 < NK) stage_half(Bt, bn+0, k2, Bc + 0);
    FENCE_BARRIER();
    LGKM0();
    __builtin_amdgcn_s_setprio(1);
#pragma unroll
    for (int m=0;m<4;++m)
#pragma unroll
      for (int n=0;n<2;++n)
#pragma unroll
        for (int ks=0;ks<2;++ks)
          acc[1][1][m][n] = __builtin_amdgcn_mfma_f32_16x16x32_bf16(
              af[m][ks], bf1[n][ks], acc[1][1][m][n], 0, 0, 0);
    __builtin_amdgcn_s_setprio(0);
    if (t == NK-2) { VMCNT(0); }                 // tail: next tile has nothing newer
    else          { VMCNT(4); }                  // tile t+1 fully landed; 2 halves fly
    FENCE_BARRIER();
    cur ^= 1;
  }

  // ---- epilogue ---------------------------------------------------------------
#pragma unroll
  for (int qm=0;qm<2;++qm)
#pragma unroll
  for (int qn=0;qn<2;++qn)
#pragma unroll
  for (int n=0;n<2;++n) {
    int col = bn + qn*128 + wc*32 + n*16 + l15;
    float bbc = BIAS_ROW ? 0.f : bias[col];
#pragma unroll
    for (int m=0;m<4;++m) {
      int row0 = bm + qm*128 + wr*64 + m*16 + l4*4;
#pragma unroll
      for (int r=0;r<4;++r) {
        float bb = BIAS_ROW ? bias[row0+r] : bbc;
        float v = (acc[qm][qn][m][n][r] + bb) * oscale;
        C[(size_t)(row0+r)*N + col] = f2bf(v);
      }
    }
  }
}

// Q / K / V^T projections, 192 blocks x 512 threads, per-z XCD-chunked swizzle.
__global__ __launch_bounds__(512, 2) void gemm_qkv256(
    const u16b* __restrict__ x1b, const u16b* __restrict__ x2b,
    const u16b* __restrict__ WT, const float* __restrict__ bq,
    const float* __restrict__ bk, const float* __restrict__ bv,
    u16b* __restrict__ QKV) {
  __shared__ __align__(16) u16b As[2*256*64];
  __shared__ __align__(16) u16b Bs[2*256*64];
  const int f = blockIdx.x;
  const int z = f >> 6;                      // 0=Q, 1=K, 2=V^T
  const int u = f & 63;
  const int w = ((u & 7) << 3) | (u >> 3);   // xcd = u&7 gets 8 contiguous tiles
  const size_t Mi = 1024*1024;
  const float QSCALE = 0.125f * 1.4426950408889634f;   // 1/sqrt(Dh) * log2(e)
  if (z == 2) {
    int bm = (w >> 4) * 256;                 // WvT rows (d)
    int bn = (w & 15) * 256;                 // tokens
    gemm256_core<true>(As, Bs, WT + 2*Mi, x2b, bv, QKV + 8*Mi,
                       4096, 1024, bm, bn, 1.0f);
  } else {
    int bm = (w >> 2) * 256;                 // tokens
    int bn = (w & 3) * 256;                  // d_model cols
    gemm256_core<false>(As, Bs, z ? x2b : x1b, WT + (size_t)z*Mi,
                        z ? bk : bq, QKV + (size_t)z*4*Mi,
                        1024, 1024, bm, bn, z ? 1.0f : QSCALE);
  }
}

// ---------------- 128-tile GEMM core (gemm_out): 2-phase dbuf pipeline --------------
template<int BN, bool OUT_F32, bool BIAS_ROW>
__device__ __forceinline__ void gemm_core(
    u16b* __restrict__ As, u16b* __restrict__ Bs,   // As[2][128*64], Bs[2][BN*64]
    const u16b* __restrict__ A, const u16b* __restrict__ Bt,
    const float* __restrict__ bias, void* __restrict__ Cv,
    int N, int K, int bm, int bn, float oscale) {
  constexpr int NT = BN / 32;                  // n-tiles per wave
  constexpr int ASTRIDE = 128*64;
  constexpr int BSTRIDE = BN*64;
  const int tid = threadIdx.x;
  const int lane = tid & 63, wave = tid >> 6;
  const int wm = wave >> 1, wn = wave & 1;
  const int l15 = lane & 15, l4 = lane >> 4;
  float4v acc[4][NT];
#pragma unroll
  for (int i=0;i<4;++i)
#pragma unroll
    for (int j=0;j<NT;++j) acc[i][j] = (float4v){0.f,0.f,0.f,0.f};

  auto stage = [&](int buf, int k0) {
#pragma unroll
    for (int j=0;j<4;++j) {                    // As: 128 rows x 8 chunks
      int idx = j*256 + tid;
      int row = idx >> 3, seg = idx & 7;
      int segg = seg ^ (row & 7);
      gl_lds16(&A[(size_t)(bm+row)*K + k0 + segg*8], &As[buf*ASTRIDE + idx*8]);
    }
#pragma unroll
    for (int j=0;j<BN/32;++j) {                // Bs: BN rows x 8 chunks
      int idx = j*256 + tid;
      int row = idx >> 3, seg = idx & 7;
      int segg = seg ^ (row & 7);
      gl_lds16(&Bt[(size_t)(bn+row)*K + k0 + segg*8], &Bs[buf*BSTRIDE + idx*8]);
    }
  };

  const int NK = K >> 6;
  stage(0, 0);
  __syncthreads();                             // drain: buf0 ready
  for (int kt = 0; kt < NK; ++kt) {
    const int cur = kt & 1;
    if (kt + 1 < NK) stage(cur ^ 1, (kt + 1) << 6);   // issue next tile's loads
    const u16b* Asb = As + cur*ASTRIDE;
    const u16b* Bsb = Bs + cur*BSTRIDE;
#pragma unroll
    for (int ks=0; ks<2; ++ks) {
      short8v af[4], bf[NT];
      const int cs = ((ks*4 + l4) ^ (l15 & 7)) * 8;
#pragma unroll
      for (int mt=0;mt<4;++mt)
        af[mt] = *(const short8v*)&Asb[(wm*64+mt*16+l15)*64 + cs];
#pragma unroll
      for (int nt=0;nt<NT;++nt)
        bf[nt] = *(const short8v*)&Bsb[(wn*(BN/2)+nt*16+l15)*64 + cs];
#pragma unroll
      for (int mt=0;mt<4;++mt)
#pragma unroll
        for (int nt=0;nt<NT;++nt)
          acc[mt][nt] = __builtin_amdgcn_mfma_f32_16x16x32_bf16(af[mt], bf[nt], acc[mt][nt], 0, 0, 0);
    }
    __syncthreads();   // drains this wave's prefetch (vmcnt 0) + all LDS reads
  }

#pragma unroll
  for (int nt=0;nt<NT;++nt) {
    int col = bn + wn*(BN/2) + nt*16 + l15;
    float bbc = BIAS_ROW ? 0.f : bias[col];
#pragma unroll
    for (int mt=0;mt<4;++mt) {
      int row0 = bm + wm*64 + mt*16 + l4*4;
#pragma unroll
      for (int r=0;r<4;++r) {
        float bb = BIAS_ROW ? bias[row0+r] : bbc;
        float v = (acc[mt][nt][r] + bb) * oscale;  // C/D: col=l15, row=l4*4+r
        if (OUT_F32) ((float*)Cv)[(size_t)(row0+r)*N + col] = v;
        else         ((u16b*)Cv)[(size_t)(row0+r)*N + col] = f2bf(v);
      }
    }
  }
}

// final projection, fp32 out; flat grid 512, XCD-swizzled
__global__ __launch_bounds__(256) void gemm_out(
    const u16b* __restrict__ A, const u16b* __restrict__ Bt,
    const float* __restrict__ bias, float* __restrict__ C) {
  __shared__ __align__(16) u16b As[2*128*64];
  __shared__ __align__(16) u16b Bs[2*64*64];
  const int f = blockIdx.x;
  const int xcd = f & 7, s = f >> 3;
  const int bm = (xcd*4 + (s >> 4)) * 128;
  const int bn = (s & 15) * 64;
  gemm_core<64,true,false>(As, Bs, A, Bt, bias, C, 1024, 1024, bm, bn, 1.0f);
}

// ---------------- flash attention: 128 q x 128 kv, 32x32 MFMA, in-register P --------
// grid (32 bh, 16 qtile). 4 waves x 32 q. Swapped QK^T via mfma_32x32x16(K,Q):
// lane holds S^T[kv][q=l31] at kv=(r&3)+8(r>>2)+4hi per 32-kv block.
// PV (R16): mfma_32x32x16 with kv->k permutation mu0=[0-3,8-11|4-7,12-15] (+16 for
// mu1): A-frag = packed d[0..3]/d[4..7] DIRECTLY (the permutation absorbs the
// 4hi offset); B-frag = two b64 V reads at the matching kv sets. Full-rate PV.
// K/V LDS double-buffered; ONE barrier per kt; tile kt+1 written to buf^1 at the
// end of iter kt (its last readers finished before barrier(kt); prefetch loads
// issued right after barrier(kt) get the whole compute phase to land).
// Vs rows padded to 132 (stride ≡ 2 mod 32 dw): b64 phases hit 16 distinct rows.
// LDS: 2*(16384 + 16896) = 66560 B -> 2 blocks/CU.
__device__ __forceinline__ void attn_load(
    const u16b* __restrict__ Kgb, const u16b* __restrict__ Vtb,
    int kvoff, int tid, short8v kreg[4], short8v vreg[4]) {
#pragma unroll
  for (int j=0; j<4; ++j) {
    int idx = j*256 + tid;
    int rowk = idx >> 3, segk = idx & 7;
    kreg[j] = *(const short8v*)&Kgb[(size_t)(kvoff+rowk)*1024 + ((segk ^ (rowk & 7))*8)];
    int rowv = idx & 63, segv = idx >> 6;   // row-major: 16-lane groups span 16 rows
    vreg[j] = *(const short8v*)&Vtb[(size_t)rowv*4096 + kvoff + segv*8];
  }
}

__global__ __launch_bounds__(256, 2) void attn_q128(
    const u16b* __restrict__ Q, const u16b* __restrict__ Kg,
    const u16b* __restrict__ Vt, u16b* __restrict__ O) {
  __shared__ __align__(16) u16b Ks[2][128*64];   // [kv][d] chunk-swizzled (^row&7)
  __shared__ __align__(16) u16b Vs[2][64*132];   // [d][kv] +8B row pad, linear cols
  const int tid = threadIdx.x;
  const int lane = tid & 63, wave = tid >> 6;
  const int l31 = lane & 31, hi = lane >> 5;
  const int bh = blockIdx.x;
  const int b = bh >> 4, h = bh & 15;
  const int q0 = blockIdx.y * 128;
  const size_t seqbase = (size_t)b * 2048;
  const int colh = h * 64;
  const u16b* Kgb = Kg + seqbase*1024 + colh;
  const u16b* Vtb = Vt + (size_t)(h*64)*4096 + (size_t)b*2048;

  // prefetch tile 0 into registers
  short8v kreg[4], vreg[4];
  attn_load(Kgb, Vtb, 0, tid, kreg, vreg);

  // Q B-fragments for 32x32x16: lane holds Q[q=l31][d = ks*16 + hi*8 + j]
  short8v qf[4];
  {
    size_t qrow = seqbase + q0 + wave*32 + l31;
#pragma unroll
    for (int ks=0; ks<4; ++ks)
      qf[ks] = *(const short8v*)&Q[qrow*1024 + colh + ks*16 + hi*8];
  }

  float16v oacc[2];
#pragma unroll
  for (int nb=0; nb<2; ++nb)
#pragma unroll
    for (int r=0; r<16; ++r) oacc[nb][r] = 0.f;
  float lsum = 0.f;

  // stage tile 0 -> buf 0 (stalls on tile-0 loads; startup only)
  {
    u16b* Kw = Ks[0]; u16b* Vw = Vs[0];
#pragma unroll
    for (int j=0; j<4; ++j) {
      int idx = j*256 + tid;
      *(short8v*)&Kw[idx*8] = kreg[j];
      int rowv = idx & 63, segv = idx >> 6;
      union { short8v s; uint2v u[2]; } tv; tv.s = vreg[j];
      *(uint2v*)&Vw[rowv*132 + segv*8]     = tv.u[0];
      *(uint2v*)&Vw[rowv*132 + segv*8 + 4] = tv.u[1];
    }
  }

  for (int kt = 0; kt < 16; ++kt) {
    __syncthreads();                 // buf[kt&1] writes visible; its prior readers done
    // prefetch tile kt+1 (lands during compute; consumed by the write below)
    if (kt < 15)
      attn_load(Kgb, Vtb, (kt+1)*128, tid, kreg, vreg);
    const u16b* Kb_ = Ks[kt & 1];
    const u16b* Vb_ = Vs[kt & 1];

    // ---- S^T = K·Q^T: sacc[kvblk] holds S^T[kv 32-block][q=l31] -------------
    float16v sacc[4];
#pragma unroll
    for (int kb=0; kb<4; ++kb)
#pragma unroll
      for (int r=0; r<16; ++r) sacc[kb][r] = 0.f;
    __builtin_amdgcn_s_setprio(1);
#pragma unroll
    for (int kb=0; kb<4; ++kb)
#pragma unroll
      for (int ks=0; ks<4; ++ks) {
        int row = kb*32 + l31;
        short8v kf = *(const short8v*)&Kb_[row*64 + (((ks*2+hi) ^ (row & 7))*8)];
        sacc[kb] = __builtin_amdgcn_mfma_f32_32x32x16_bf16(kf, qf[ks], sacc[kb], 0, 0, 0);
      }
    __builtin_amdgcn_s_setprio(0);

    // ---- per kv-block: exp2 -> packed P -> PV as 2 kv-permuted 32x32x16 -----
#pragma unroll
    for (int kb=0; kb<4; ++kb) {
      float e[16];
#pragma unroll
      for (int r=0; r<16; ++r) e[r] = exp2_fast(sacc[kb][r]);
#pragma unroll
      for (int r=0; r<16; ++r) lsum += e[r];
      unsigned int d[8];
#pragma unroll
      for (int i=0; i<8; ++i)   // pack hi16(e[2i]) | hi16(e[2i+1])<<16 (trunc bf16)
        d[i] = __builtin_amdgcn_perm(__float_as_uint(e[2*i+1]),
                                     __float_as_uint(e[2*i]), 0x07060302u);
      // A-frags: mu0 maps k(0..15) -> kv [0-3,8-11 | 4-7,12-15] (+4hi absorbed):
      // lane's frag is exactly d[0..3]; mu1 = mu0+16 -> d[4..7].
      union { unsigned int u[4]; short8v s; } pa0, pa1;
      pa0.u[0]=d[0]; pa0.u[1]=d[1]; pa0.u[2]=d[2]; pa0.u[3]=d[3];
      pa1.u[0]=d[4]; pa1.u[1]=d[5]; pa1.u[2]=d[6]; pa1.u[3]=d[7];
      __builtin_amdgcn_s_setprio(1);
#pragma unroll
      for (int nb=0; nb<2; ++nb) {
        int row = nb*32 + l31;          // V row = d
        const u16b* vb = &Vb_[row*132 + kb*32 + hi*4];
        union { short4v h[2]; short8v s; } v0, v1;
        v0.h[0] = *(const short4v*)(vb);        // kv kb*32 + hi*4 + {0..3}
        v0.h[1] = *(const short4v*)(vb + 8);    // kv +8  (k = 4..7 | 12..15)
        v1.h[0] = *(const short4v*)(vb + 16);   // kv +16
        v1.h[1] = *(const short4v*)(vb + 24);   // kv +24
        oacc[nb] = __builtin_amdgcn_mfma_f32_32x32x16_bf16(pa0.s, v0.s, oacc[nb], 0, 0, 0);
        oacc[nb] = __builtin_amdgcn_mfma_f32_32x32x16_bf16(pa1.s, v1.s, oacc[nb], 0, 0, 0);
      }
      __builtin_amdgcn_s_setprio(0);
    }

    // ---- write tile kt+1 -> buf[(kt+1)&1] (all its readers finished pre-barrier)
    if (kt < 15) {
      u16b* Kw = Ks[(kt+1) & 1]; u16b* Vw = Vs[(kt+1) & 1];
#pragma unroll
      for (int j=0; j<4; ++j) {
        int idx = j*256 + tid;
        *(short8v*)&Kw[idx*8] = kreg[j];
        int rowv = idx & 63, segv = idx >> 6;
        union { short8v s; uint2v u[2]; } tv; tv.s = vreg[j];
        *(uint2v*)&Vw[rowv*132 + segv*8]     = tv.u[0];
        *(uint2v*)&Vw[rowv*132 + segv*8 + 4] = tv.u[1];
      }
    }
  }

  // ---- epilogue: l[q] = own-half sum + partner-half sum; normalize, store ----
  float ltot = lsum + __shfl_xor(lsum, 32, 64);   // lane l holds l[q=l31]
#pragma unroll
  for (int r=0; r<16; ++r) {
    int qloc = (r & 3) + 8*(r >> 2) + 4*hi;       // oacc row -> q within wave tile
    float lv = __shfl(ltot, qloc, 64);
    float inv = 1.0f / lv;
    size_t row = seqbase + q0 + wave*32 + qloc;
    O[row*1024 + colh +      l31] = f2bf(oacc[0][r] * inv);
    O[row*1024 + colh + 32 + l31] = f2bf(oacc[1][r] * inv);
  }
}

extern "C" void kernel_launch(void* const* d_in, const int* in_sizes, int n_in,
                              void* d_out, int out_size, void* d_ws, size_t ws_size,
                              hipStream_t stream) {
  const float* x1 = (const float*)d_in[0];
  const float* x2 = (const float*)d_in[1];
  const float* Wq = (const float*)d_in[2];
  const float* bq = (const float*)d_in[3];
  const float* Wk = (const float*)d_in[4];
  const float* bk = (const float*)d_in[5];
  const float* Wv = (const float*)d_in[6];
  const float* bv = (const float*)d_in[7];
  const float* Wo = (const float*)d_in[8];
  const float* bo = (const float*)d_in[9];
  (void)in_sizes; (void)n_in; (void)out_size; (void)ws_size;

  u16b* ws = (u16b*)d_ws;
  const size_t Mi = 1024*1024;
  u16b* WT  = ws;               // WqT,WkT,WvT contiguous + WoT
  u16b* WoT = ws + 3*Mi;
  u16b* x1b = ws + 4*Mi;        // Cx aliases after Q-gemm consumed it
  u16b* x2b = ws + 8*Mi;
  u16b* QKV = ws + 12*Mi;       // Qb, Kb, Vtb (4Mi each) -> 48 MiB total
  u16b* Qb  = QKV;
  u16b* Kb  = QKV + 4*Mi;
  u16b* Vtb = QKV + 8*Mi;       // Vt[h*64+d][b*2048+kv], stride 4096
  u16b* Cx  = x1b;

  prep<<<dim3(1024,6), 256, 0, stream>>>(x1, x2, Wq, Wk, Wv, Wo, x1b, x2b, WT);

  gemm_qkv256<<<dim3(192), 512, 0, stream>>>(x1b, x2b, WT, bq, bk, bv, QKV);

  attn_q128<<<dim3(32,16), 256, 0, stream>>>(Qb, Kb, Vtb, Cx);

  gemm_out<<<dim3(512), 256, 0, stream>>>(Cx, WoT, bo, (float*)d_out);
}